// Round 4
// baseline (335.420 us; speedup 1.0000x reference)
//
#include <hip/hip_runtime.h>

// out[p][f] = sum_s x[p][s] * K[s][f];  P = 393216 patches, K 64x64 fp32.
//
// R3 post-mortem: correct traffic (WRITE exactly = output, no spill) but
// Occupancy 14.6% (50 KB LDS, 2-wave blocks -> 1.5 waves/SIMD) and VALUBusy
// 22%: inner-loop s_load(K)+ds_read(x) both drain on lgkmcnt with nothing to
// hide the stall. Fix = occupancy:
//  - 256-thread blocks; wave pair splits f-space (acc[32], one pass over s).
//  - Single 33.3 KB LDS slab (pad-65), reused for the output transpose ->
//    4 blocks/CU x 4 waves = 16 waves/CU (50%), 4 waves/SIMD hide lgkm.
//  - K stays scalar (s_load_dwordx16, wave-uniform, L1-scalar-hot);
//    v_fmac_f32 acc, sK, vX = 1 SGPR read per instr (legal).
// Cycle model/CU: FMA 49K cyc = 20.5us floor, DS ~18us (parallel pipe),
// HBM ~150MB eff ~24-30us -> predict 35-45us.

#define THREADS 256
#define PPB     128
#define XS      65   // pad: bank (p+s)%32 -> worst 2-way (free, m136)

__global__ __launch_bounds__(THREADS)
void dct_kernel(const float* __restrict__ x,
                const float* __restrict__ Kmat,
                float* __restrict__ out) {
    __shared__ float lx[PPB * XS];   // 33,280 B -> 4 blocks/CU

    const int tid  = threadIdx.x;
    const int lane = tid & 63;
    const int wave = tid >> 6;       // 0..3
    const int pair = wave >> 1;      // patch group 0/1
    const int half = wave & 1;       // f half 0/1
    const long long tile = (long long)blockIdx.x * PPB;

    // ---- stage 128 patches (8192 floats) coalesced; b32 writes (odd pad) ----
    const float4* src = (const float4*)(x + tile * 64);
#pragma unroll
    for (int i = 0; i < 8; ++i) {
        int f4 = tid + i * THREADS;      // 0..2047
        float4 v = src[f4];
        int p = f4 >> 4;
        int s = (f4 & 15) << 2;
        float* d = &lx[p * XS + s];
        d[0] = v.x; d[1] = v.y; d[2] = v.z; d[3] = v.w;
    }
    __syncthreads();

    // ---- compute: lane owns patch pair*64+lane, f in [half*32, half*32+32) ----
    const int p = pair * 64 + lane;
    const float* xrow = &lx[p * XS];

    float acc[32];
#pragma unroll
    for (int j = 0; j < 32; ++j) acc[j] = 0.f;

#pragma unroll 4
    for (int s = 0; s < 64; ++s) {
        float xs = xrow[s];                            // ds_read_b32, 2-way
        const float* Kr = Kmat + s * 64 + half * 32;   // uniform -> s_load x16
#pragma unroll
        for (int j = 0; j < 32; ++j)
            acc[j] = fmaf(xs, Kr[j], acc[j]);          // v_fmac v, s, v
    }

    // ---- transpose through the SAME slab (x fully consumed) ----
    __syncthreads();
#pragma unroll
    for (int j = 0; j < 32; ++j)
        lx[p * XS + half * 32 + j] = acc[j];  // banks (p+j)%32: 2-way free
    __syncthreads();

    // ---- coalesced store: 8192 floats, 1 KB per wave-instr ----
    float* ob = out + tile * 64;
#pragma unroll
    for (int i = 0; i < 32; ++i) {
        int idx = tid + i * THREADS;   // consecutive -> coalesced
        int pp = idx >> 6;
        int ff = idx & 63;
        ob[idx] = lx[pp * XS + ff];    // banks walk +1 per lane: conflict-free
    }
}

extern "C" void kernel_launch(void* const* d_in, const int* in_sizes, int n_in,
                              void* d_out, int out_size, void* d_ws, size_t ws_size,
                              hipStream_t stream) {
    const float* x = (const float*)d_in[0];   // (8,3,1024,1024) fp32
    const float* K = (const float*)d_in[1];   // (64,64) fp32
    float* out = (float*)d_out;

    const int total = in_sizes[0];            // 25,165,824
    const int num_patches = total / 64;       // 393,216
    const int blocks = num_patches / PPB;     // 3072, exact

    dct_kernel<<<blocks, THREADS, 0, stream>>>(x, K, out);
}

// Round 5
// 190.928 us; speedup vs baseline: 1.7568x; 1.7568x over previous
//
#include <hip/hip_runtime.h>

// out[p][f] = sum_s x[p][s] * K[s][f];  P = 393216 patches, K 64x64 fp32.
//
// R4 post-mortem: `half = (tid>>6)&1` in the K address defeated uniformity
// analysis -> K loads became per-lane VMEM loads (~200cyc L2 latency on the
// critical path; VALUBusy 11%, dur 222us). R3 was fast(er) only because its
// K offset was a loop counter (provably uniform -> s_load_dwordx16).
//
// Fix: readfirstlane(half) -> SGPR -> scalar K path restored, KEEPING R4's
// occupancy (33KB LDS, 4 blk/CU x 4 waves = 4 waves/SIMD hides lgkm).
//  - lane = patch; x rows in LDS pad-65 (2-way banked = free, m136).
//  - K[s][f]: s_load_dwordx16, scalar-cache-hot (16 KB total).
//  - acc[32]/lane, one pass over s; structurally spill-free.
//  - Epilogue transposes through the same slab; coalesced 1KB stores.
// Model: FMA floor 20.5us, HBM ~24us (L3 absorbs half fetch), DS ~7us
// -> predict 35-45us.

#define THREADS 256
#define PPB     128
#define XS      65   // pad: worst 2-way bank alias (free)

__global__ __launch_bounds__(THREADS)
void dct_kernel(const float* __restrict__ x,
                const float* __restrict__ Kmat,
                float* __restrict__ out) {
    __shared__ float lx[PPB * XS];   // 33,280 B -> 4 blocks/CU

    const int tid  = threadIdx.x;
    const int lane = tid & 63;
    const int wave = tid >> 6;                                   // 0..3
    const int pair = wave >> 1;                                  // patch group
    const int half = __builtin_amdgcn_readfirstlane(wave & 1);   // SGPR! -> s_load K
    const long long tile = (long long)blockIdx.x * PPB;

    // ---- stage 128 patches (8192 floats) coalesced; b32 writes (odd pad) ----
    const float4* src = (const float4*)(x + tile * 64);
#pragma unroll
    for (int i = 0; i < 8; ++i) {
        int f4 = tid + i * THREADS;      // 0..2047
        float4 v = src[f4];
        int p = f4 >> 4;
        int s = (f4 & 15) << 2;
        float* d = &lx[p * XS + s];
        d[0] = v.x; d[1] = v.y; d[2] = v.z; d[3] = v.w;
    }
    __syncthreads();

    // ---- compute: lane owns patch pair*64+lane, f in [half*32, half*32+32) ----
    const int p = pair * 64 + lane;
    const float* xrow = &lx[p * XS];
    const float* Kbase = Kmat + half * 32;   // SGPR base -> uniform

    float acc[32];
#pragma unroll
    for (int j = 0; j < 32; ++j) acc[j] = 0.f;

#pragma unroll 4
    for (int s = 0; s < 64; ++s) {
        float xs = xrow[s];                      // ds_read_b32, 2-way
        const float* Kr = Kbase + s * 64;        // uniform -> s_load_dwordx16
#pragma unroll
        for (int j = 0; j < 32; ++j)
            acc[j] = fmaf(xs, Kr[j], acc[j]);    // v_fmac acc, sK, vX
    }

    // ---- transpose through the SAME slab (x fully consumed) ----
    __syncthreads();
#pragma unroll
    for (int j = 0; j < 32; ++j)
        lx[p * XS + half * 32 + j] = acc[j];  // banks (p+j)%32: 2-way free
    __syncthreads();

    // ---- coalesced store: 8192 floats, 1 KB per wave-instr ----
    float* ob = out + tile * 64;
#pragma unroll
    for (int i = 0; i < 32; ++i) {
        int idx = tid + i * THREADS;   // consecutive -> coalesced
        int pp = idx >> 6;
        int ff = idx & 63;
        ob[idx] = lx[pp * XS + ff];    // banks walk +1 per lane: conflict-free
    }
}

extern "C" void kernel_launch(void* const* d_in, const int* in_sizes, int n_in,
                              void* d_out, int out_size, void* d_ws, size_t ws_size,
                              hipStream_t stream) {
    const float* x = (const float*)d_in[0];   // (8,3,1024,1024) fp32
    const float* K = (const float*)d_in[1];   // (64,64) fp32
    float* out = (float*)d_out;

    const int total = in_sizes[0];            // 25,165,824
    const int num_patches = total / 64;       // 393,216
    const int blocks = num_patches / PPB;     // 3072, exact

    dct_kernel<<<blocks, THREADS, 0, stream>>>(x, K, out);
}

// Round 6
// 174.506 us; speedup vs baseline: 1.9221x; 1.0941x over previous
//
#include <hip/hip_runtime.h>

// out[p][f] = sum_s x[p][s] * K[s][f];  P=393216, K 64x64 fp32.
//
// R5 post-mortem: VALU path is pinned at ~31% busy: K via SMEM forces
// lgkmcnt(0) (SMEM returns OOO) which drains all prefetches; K via LDS costs
// a measured ~12cyc/b128 broadcast on the per-CU-shared DS pipe (R2 evidence:
// 6.29M b128 x 12cyc/256CU = 118us). Restructure to MFMA (Guideline 10):
// bf16 hi/lo split (xh+xl)*(Kh+Kl), keep 3 terms -> fp32-grade accuracy
// (dropped xl*Kl ~ 2^-18 rel; absmax ~1e-3 << 0.11 threshold). Compute:
// 3 x 3.22GF = 9.7GF ~ 5us at MFMA rate -> purely HBM-bound (~24us floor).
//
// Layouts (HW-verified per guide m89/m120):
//   A frag 16x16x32: m = lane&15, k = quad*8+j   (quad = lane>>4)
//   B frag:          n = lane&15, k = quad*8+j
//   C/D:             col = lane&15, row = quad*4+reg
// Block = 64 patches, 4 waves, wave = 16 patches x 64 f (4 f-tiles).
// LDS: x tile fp32 [64][68] (b128-aligned reads, all-32-bank pattern) +
// K bf16 hi/lo frag buffers (lane-linear 16B = conflict-free) = 33.8 KB
// -> 4 blocks/CU, 16 waves/CU.

#define THREADS 256
#define PPW 16
#define PPB 64
#define XS  68   // floats; multiple of 4 (b128 align); frag reads hit all 32 banks

typedef __attribute__((ext_vector_type(8))) short bf16x8;
typedef __attribute__((ext_vector_type(4))) float f32x4;

static __device__ __forceinline__ unsigned short bf16_rne(float f) {
    unsigned int u = __float_as_uint(f);
    u += 0x7fffu + ((u >> 16) & 1u);
    return (unsigned short)(u >> 16);
}
static __device__ __forceinline__ float bf16f(unsigned short h) {
    return __uint_as_float((unsigned int)h << 16);
}

__global__ __launch_bounds__(THREADS)
void dct_kernel(const float* __restrict__ x,
                const float* __restrict__ Kmat,
                float* __restrict__ out) {
    __shared__ float xt[PPB * XS];        // 17,408 B
    __shared__ short bhi[8 * 64 * 8];     //  8,192 B  [combo][lane][j]
    __shared__ short blo[8 * 64 * 8];     //  8,192 B

    const int tid  = threadIdx.x;
    const int lane = tid & 63;
    const int wv   = tid >> 6;        // 0..3
    const int l15  = lane & 15;
    const int quad = lane >> 4;       // 0..3
    const long long tile = (long long)blockIdx.x * PPB;

    // ---- stage this wave's 16 patches (4 KB, fully coalesced) ----
    const float4* src = (const float4*)(x + (tile + (long long)wv * PPW) * 64);
#pragma unroll
    for (int i = 0; i < 4; ++i) {
        int f4 = i * 64 + lane;                      // 0..255
        float4 v = src[f4];
        float* d = &xt[(wv * PPW + (f4 >> 4)) * XS + ((f4 & 15) << 2)];
        d[0] = v.x; d[1] = v.y; d[2] = v.z; d[3] = v.w;   // merges to b128
    }

    // ---- build K bf16 hi/lo B-fragments; wave wv builds combos 2wv,2wv+1 ----
    // combo = kc*4 + ft ; lane holds B[k = kc*32+quad*8+j][n = ft*16+l15]
#pragma unroll
    for (int cc = 0; cc < 2; ++cc) {
        const int combo = wv * 2 + cc;
        const int kc = combo >> 2, ft = combo & 3;
        short hh[8], ll[8];
#pragma unroll
        for (int j = 0; j < 8; ++j) {
            float v = Kmat[(kc * 32 + quad * 8 + j) * 64 + ft * 16 + l15];
            unsigned short h = bf16_rne(v);
            hh[j] = (short)h;
            ll[j] = (short)bf16_rne(v - bf16f(h));
        }
        *(bf16x8*)&bhi[(combo * 64 + lane) * 8] = *(bf16x8*)hh;  // lane-linear 16B
        *(bf16x8*)&blo[(combo * 64 + lane) * 8] = *(bf16x8*)ll;
    }
    __syncthreads();

    // ---- compute: wave's 16 patches x 64 f via 24 MFMAs ----
    f32x4 acc[4];
#pragma unroll
    for (int t = 0; t < 4; ++t) acc[t] = (f32x4){0.f, 0.f, 0.f, 0.f};

#pragma unroll
    for (int kc = 0; kc < 2; ++kc) {
        // A frag source: x[p = wv*16 + l15][kc*32 + quad*8 + j], 8 consecutive
        const float* ap = &xt[(wv * PPW + l15) * XS + kc * 32 + quad * 8];
        float av[8];
        *(float4*)&av[0] = *(const float4*)ap;        // aligned: XS%4==0
        *(float4*)&av[4] = *(const float4*)(ap + 4);
        short ah[8], al[8];
#pragma unroll
        for (int j = 0; j < 8; ++j) {
            unsigned short h = bf16_rne(av[j]);
            ah[j] = (short)h;
            al[j] = (short)bf16_rne(av[j] - bf16f(h));
        }
        bf16x8 Ahi = *(bf16x8*)ah;
        bf16x8 Alo = *(bf16x8*)al;
#pragma unroll
        for (int ft = 0; ft < 4; ++ft) {
            const int combo = kc * 4 + ft;
            bf16x8 Bhi = *(const bf16x8*)&bhi[(combo * 64 + lane) * 8];
            bf16x8 Blo = *(const bf16x8*)&blo[(combo * 64 + lane) * 8];
            acc[ft] = __builtin_amdgcn_mfma_f32_16x16x32_bf16(Ahi, Bhi, acc[ft], 0, 0, 0);
            acc[ft] = __builtin_amdgcn_mfma_f32_16x16x32_bf16(Alo, Bhi, acc[ft], 0, 0, 0);
            acc[ft] = __builtin_amdgcn_mfma_f32_16x16x32_bf16(Ahi, Blo, acc[ft], 0, 0, 0);
        }
    }

    // ---- epilogue: C/D layout col=l15, row=quad*4+r; 64B segments x4/instr ----
    float* ob = out + (tile + (long long)wv * PPW) * 64;
#pragma unroll
    for (int ft = 0; ft < 4; ++ft)
#pragma unroll
        for (int r = 0; r < 4; ++r)
            ob[(quad * 4 + r) * 64 + ft * 16 + l15] = acc[ft][r];
}

extern "C" void kernel_launch(void* const* d_in, const int* in_sizes, int n_in,
                              void* d_out, int out_size, void* d_ws, size_t ws_size,
                              hipStream_t stream) {
    const float* x = (const float*)d_in[0];   // (8,3,1024,1024) fp32
    const float* K = (const float*)d_in[1];   // (64,64) fp32
    float* out = (float*)d_out;

    const int total = in_sizes[0];            // 25,165,824
    const int num_patches = total / 64;       // 393,216
    const int blocks = num_patches / PPB;     // 6,144, exact

    dct_kernel<<<blocks, THREADS, 0, stream>>>(x, K, out);
}